// Round 1
// baseline (1784.720 us; speedup 1.0000x reference)
//
#include <hip/hip_runtime.h>
#include <hip/hip_bf16.h>
#include <cstdint>
#include <cstddef>

// Problem sizes (fixed)
#define B_SZ 8192
#define P_SZ 8
#define M_SZ 2048
#define C_SZ 1024

using bfrag = __attribute__((ext_vector_type(8))) short;          // 8 bf16 = 4 VGPR (MFMA A/B)
using facc  = __attribute__((ext_vector_type(4))) float;          // MFMA C/D frag
using u16x4 = __attribute__((ext_vector_type(4))) unsigned short;

__device__ __forceinline__ unsigned short f2bf(float x) {
    union { __hip_bfloat16 h; unsigned short u; } cv;
    cv.h = __float2bfloat16(x);   // RNE
    return cv.u;
}

// ---------------- pre-pass: fp32 -> bf16 conversions ----------------
__global__ void cvt_q_kernel(const float* __restrict__ in, unsigned short* __restrict__ q) {
    const size_t i = (size_t)blockIdx.x * blockDim.x + threadIdx.x;   // one float4 per thread
    const float4 v = ((const float4*)in)[i];
    u16x4 o = { f2bf(v.x), f2bf(v.y), f2bf(v.z), f2bf(v.w) };
    ((u16x4*)q)[i] = o;
}

// W fp32 [p][m][c] -> wb bf16 [p][m][c] and wt bf16 [p][c][m] (32x32 LDS tile transpose)
__global__ void cvt_w_kernel(const float* __restrict__ w,
                             unsigned short* __restrict__ wb,
                             unsigned short* __restrict__ wt) {
    __shared__ float t[32][33];
    const int bid = blockIdx.x;
    const int p  = bid >> 11;              // 2048 tiles per p (64 m-tiles * 32 c-tiles)
    const int m0 = ((bid >> 5) & 63) << 5;
    const int c0 = (bid & 31) << 5;
    const int tx = threadIdx.x & 7;        // c quad
    const int ty = threadIdx.x >> 3;       // m row 0..31
    const float4 v = *(const float4*)(w + ((size_t)p*M_SZ + m0 + ty)*C_SZ + c0 + tx*4);
    u16x4 o = { f2bf(v.x), f2bf(v.y), f2bf(v.z), f2bf(v.w) };
    *(u16x4*)(wb + ((size_t)p*M_SZ + m0 + ty)*C_SZ + c0 + tx*4) = o;
    t[ty][tx*4+0] = v.x; t[ty][tx*4+1] = v.y; t[ty][tx*4+2] = v.z; t[ty][tx*4+3] = v.w;
    __syncthreads();
    float4 u2;
    u2.x = t[tx*4+0][ty]; u2.y = t[tx*4+1][ty]; u2.z = t[tx*4+2][ty]; u2.w = t[tx*4+3][ty];
    u16x4 o2 = { f2bf(u2.x), f2bf(u2.y), f2bf(u2.z), f2bf(u2.w) };
    *(u16x4*)(wt + ((size_t)p*C_SZ + c0 + ty)*M_SZ + m0 + tx*4) = o2;
}

// ---------------- main fused kernel ----------------
// Block: 512 threads (8 waves), BR=64 rows of one p. Loop 64 m-tiles of MT=32.
// GEMM1: S[64][32] = Q(bf16 regs) * Ws^T, 2-way K-split per wave pair, LDS exchange.
// softmax: exp(s) (no max needed: |s| <~ 4), denom via shuffle + LDS atomicAdd.
// GEMM2: O[64][1024] += P(bf16 LDS) * W via WsT[c][m] tile. Final: O/denom.
constexpr int NTHREADS = 512;
constexpr int BR = 64;
constexpr int MT = 32;
constexpr int NT = M_SZ / MT;            // 64

constexpr int WS_OFF    = 0;             // Ws  [32 m][1024 c] bf16, XOR-swizzled rows: 65536 B
constexpr int WST_OFF   = 65536;         // WsT [1024 c][40 m-pitch] bf16 (pitch 80 B): 81920 B
constexpr int PS_OFF    = 147456;        // Ps  [64 b][40 m-pitch] bf16 (pitch 80 B): 5120 B
constexpr int SRED_OFF  = 152576;        // Sred[4 fr][2 slot][16][16] f32: 8192 B
constexpr int DEN_OFF   = 160768;        // denom[64] f32: 256 B
constexpr int LDS_BYTES = 161024;        // <= 160 KiB

template<bool USE_WS>
__global__ __launch_bounds__(NTHREADS, 2)
void emu_main(const float* __restrict__ inF, const float* __restrict__ wF,
              const unsigned short* __restrict__ qB,
              const unsigned short* __restrict__ wB,
              const unsigned short* __restrict__ wtB,
              float* __restrict__ out)
{
    extern __shared__ char lds[];
    const int tid  = threadIdx.x;
    const int lane = tid & 63;
    const int wid  = tid >> 6;
    const int fr   = wid >> 1;     // 0..3: 16-row group
    const int kh   = wid & 1;      // GEMM1 K-half / GEMM2 c-half
    const int g    = lane >> 4;    // 0..3
    const int l15  = lane & 15;

    const int p    = blockIdx.x & 7;          // p pinned per XCD (round-robin dispatch)
    const int row0 = (blockIdx.x >> 3) * BR;

    if (tid < 64) ((float*)(lds + DEN_OFF))[tid] = 0.0f;

    // ---- preload Q fragments (tile-invariant): rows fr*16+l15, K-half kh ----
    bfrag qreg[16];
    {
        const int qrow = row0 + fr*16 + l15;
        if constexpr (USE_WS) {
            const unsigned short* qp = qB + (size_t)qrow*C_SZ + kh*512 + g*8;
            #pragma unroll
            for (int ks = 0; ks < 16; ++ks)
                qreg[ks] = *(const bfrag*)(qp + ks*32);
        } else {
            const float* qp = inF + (size_t)qrow*C_SZ + kh*512 + g*8;
            #pragma unroll
            for (int ks = 0; ks < 16; ++ks) {
                float4 a = *(const float4*)(qp + ks*32);
                float4 b = *(const float4*)(qp + ks*32 + 4);
                bfrag r;
                r[0]=(short)f2bf(a.x); r[1]=(short)f2bf(a.y);
                r[2]=(short)f2bf(a.z); r[3]=(short)f2bf(a.w);
                r[4]=(short)f2bf(b.x); r[5]=(short)f2bf(b.y);
                r[6]=(short)f2bf(b.z); r[7]=(short)f2bf(b.w);
                qreg[ks] = r;
            }
        }
    }

    facc acc[32];
    #pragma unroll
    for (int i = 0; i < 32; ++i) acc[i] = facc{0.f, 0.f, 0.f, 0.f};

    for (int mt = 0; mt < NT; ++mt) {
        // ---------- stage Ws (swizzled) + WsT ----------
        if constexpr (USE_WS) {
            const unsigned short* wsrc = wB + ((size_t)p*M_SZ + (size_t)mt*MT)*C_SZ;
            #pragma unroll
            for (int k = 0; k < 8; ++k) {
                const int m    = (tid >> 7) + 4*k;      // 0..31
                const int slot = tid & 127;             // 16B chunk within row
                bfrag v = *(const bfrag*)(wsrc + (size_t)m*C_SZ + slot*8);
                *(bfrag*)(lds + WS_OFF + m*2048 + ((slot ^ (m & 7)) << 4)) = v;
            }
            const unsigned short* wtsrc = wtB + (size_t)p*C_SZ*M_SZ + (size_t)mt*MT;
            #pragma unroll
            for (int k = 0; k < 8; ++k) {
                const int c  = (tid >> 2) + 128*k;      // 0..1023
                const int mh = tid & 3;                 // 8-elem chunk of m
                bfrag v = *(const bfrag*)(wtsrc + (size_t)c*M_SZ + mh*8);
                *(bfrag*)(lds + WST_OFF + c*80 + mh*16) = v;
            }
            __syncthreads();                            // B1
        } else {
            const float* wsrcf = wF + ((size_t)p*M_SZ + (size_t)mt*MT)*C_SZ;
            #pragma unroll
            for (int k = 0; k < 8; ++k) {
                const int m    = (tid >> 7) + 4*k;
                const int slot = tid & 127;
                const float* s = wsrcf + (size_t)m*C_SZ + slot*8;
                float4 a = *(const float4*)(s);
                float4 b = *(const float4*)(s + 4);
                bfrag v;
                v[0]=(short)f2bf(a.x); v[1]=(short)f2bf(a.y);
                v[2]=(short)f2bf(a.z); v[3]=(short)f2bf(a.w);
                v[4]=(short)f2bf(b.x); v[5]=(short)f2bf(b.y);
                v[6]=(short)f2bf(b.z); v[7]=(short)f2bf(b.w);
                *(bfrag*)(lds + WS_OFF + m*2048 + ((slot ^ (m & 7)) << 4)) = v;
            }
            __syncthreads();                            // B0
            {   // transpose Ws -> WsT inside LDS
                const int m  = tid & 31;
                const int c0 = (tid >> 5) * 64;
                #pragma unroll
                for (int q8 = 0; q8 < 8; ++q8) {
                    const int cbase = c0 + q8*8;
                    const int slot  = cbase >> 3;
                    bfrag v = *(const bfrag*)(lds + WS_OFF + m*2048 + ((slot ^ (m & 7)) << 4));
                    #pragma unroll
                    for (int i = 0; i < 8; ++i)
                        *(unsigned short*)(lds + WST_OFF + (cbase + i)*80 + m*2) =
                            (unsigned short)v[i];
                }
            }
            __syncthreads();                            // B1
        }

        // ---------- GEMM1: partial S over K-half kh, frags fm=0,1 ----------
        facc s0 = facc{0.f,0.f,0.f,0.f};
        facc s1 = facc{0.f,0.f,0.f,0.f};
        {
            const char* wsrow = lds + WS_OFF + l15*2048;
            const int xr    = (l15 & 7) << 4;
            const int cbase = kh*1024 + g*16;
            #pragma unroll
            for (int ks = 0; ks < 16; ++ks) {
                const int cbx = (cbase + ks*64) ^ xr;
                bfrag b0 = *(const bfrag*)(wsrow + cbx);            // m = l15
                bfrag b1 = *(const bfrag*)(wsrow + 32768 + cbx);    // m = 16+l15
                s0 = __builtin_amdgcn_mfma_f32_16x16x32_bf16(qreg[ks], b0, s0, 0, 0, 0);
                s1 = __builtin_amdgcn_mfma_f32_16x16x32_bf16(qreg[ks], b1, s1, 0, 0, 0);
            }
        }
        // write partial for fm = kh^1 to exchange slot
        {
            facc sx = kh ? s0 : s1;
            float* base = (float*)(lds + SRED_OFF) + (fr*2 + (kh ^ 1))*256;
            #pragma unroll
            for (int j = 0; j < 4; ++j)
                base[(g*4 + j)*16 + l15] = sx[j];
        }
        __syncthreads();                                // B2

        // ---------- finalize fm=kh: add partner, exp, denom, write Ps ----------
        {
            facc mine = kh ? s1 : s0;
            const float* base = (float*)(lds + SRED_OFF) + (fr*2 + kh)*256;
            float ps[4];
            #pragma unroll
            for (int j = 0; j < 4; ++j)
                ps[j] = __expf(mine[j] + base[(g*4 + j)*16 + l15]);
            #pragma unroll
            for (int j = 0; j < 4; ++j)
                *(unsigned short*)(lds + PS_OFF + (fr*16 + g*4 + j)*80 + (kh*16 + l15)*2)
                    = f2bf(ps[j]);
            #pragma unroll
            for (int j = 0; j < 4; ++j) {
                float v = ps[j];
                v += __shfl_xor(v, 1);
                v += __shfl_xor(v, 2);
                v += __shfl_xor(v, 4);
                v += __shfl_xor(v, 8);
                if (l15 == 0)
                    atomicAdd((float*)(lds + DEN_OFF) + (fr*16 + g*4 + j), v);
            }
        }
        __syncthreads();                                // B3

        // ---------- GEMM2: O[16 rows fr][512 c-half kh] += P * W ----------
        {
            bfrag a2 = *(const bfrag*)(lds + PS_OFF + (fr*16 + l15)*80 + g*16);
            const char* wtbase = lds + WST_OFF + (size_t)(kh*512 + l15)*80 + g*16;
            #pragma unroll
            for (int cf = 0; cf < 32; ++cf) {
                bfrag b = *(const bfrag*)(wtbase + cf*1280);   // 16 c-rows * 80 B
                acc[cf] = __builtin_amdgcn_mfma_f32_16x16x32_bf16(a2, b, acc[cf], 0, 0, 0);
            }
        }
        __syncthreads();                                // B4 (protects next-tile staging)
    }

    // ---------- epilogue: divide by denom, store ----------
    float rinv[4];
    #pragma unroll
    for (int j = 0; j < 4; ++j)
        rinv[j] = 1.0f / ((const float*)(lds + DEN_OFF))[fr*16 + g*4 + j];

    #pragma unroll
    for (int cf = 0; cf < 32; ++cf) {
        const int c = kh*512 + cf*16 + l15;
        #pragma unroll
        for (int j = 0; j < 4; ++j) {
            const size_t b = (size_t)row0 + fr*16 + g*4 + j;
            out[(b*P_SZ + p)*C_SZ + c] = acc[cf][j] * rinv[j];
        }
    }
}

// ---------------- launcher ----------------
extern "C" void kernel_launch(void* const* d_in, const int* in_sizes, int n_in,
                              void* d_out, int out_size, void* d_ws, size_t ws_size,
                              hipStream_t stream)
{
    (void)in_sizes; (void)n_in; (void)out_size;
    const float* inF = (const float*)d_in[0];
    const float* wF  = (const float*)d_in[1];
    float* out = (float*)d_out;

    const size_t wbElems = (size_t)P_SZ * M_SZ * C_SZ;   // 16M
    const size_t qElems  = (size_t)B_SZ * C_SZ;          // 8M
    const size_t need = (wbElems*2 + qElems) * sizeof(unsigned short);  // 80 MB

    const dim3 grid((B_SZ / BR) * P_SZ);   // 1024 blocks: p = bid&7 (XCD-pinned)
    const dim3 blk(NTHREADS);

    if (ws_size >= need) {
        unsigned short* wb = (unsigned short*)d_ws;
        unsigned short* wt = wb + wbElems;
        unsigned short* qb = wt + wbElems;
        cvt_q_kernel<<<(unsigned)(qElems/4/256), 256, 0, stream>>>(inF, qb);
        cvt_w_kernel<<<P_SZ*64*32, 256, 0, stream>>>(wF, wb, wt);
        hipFuncSetAttribute(reinterpret_cast<const void*>(&emu_main<true>),
                            hipFuncAttributeMaxDynamicSharedMemorySize, LDS_BYTES);
        emu_main<true><<<grid, blk, LDS_BYTES, stream>>>(inF, wF, qb, wb, wt, out);
    } else {
        hipFuncSetAttribute(reinterpret_cast<const void*>(&emu_main<false>),
                            hipFuncAttributeMaxDynamicSharedMemorySize, LDS_BYTES);
        emu_main<false><<<grid, blk, LDS_BYTES, stream>>>(inF, wF, nullptr, nullptr, nullptr, out);
    }
}

// Round 2
// 1293.349 us; speedup vs baseline: 1.3799x; 1.3799x over previous
//
#include <hip/hip_runtime.h>
#include <hip/hip_bf16.h>
#include <cstdint>
#include <cstddef>

// Problem sizes (fixed)
#define B_SZ 8192
#define P_SZ 8
#define M_SZ 2048
#define C_SZ 1024

using bfrag = __attribute__((ext_vector_type(8))) short;          // 8 bf16 = 4 VGPR (MFMA A/B)
using facc  = __attribute__((ext_vector_type(4))) float;          // MFMA C/D frag
using u16x4 = __attribute__((ext_vector_type(4))) unsigned short;

typedef __attribute__((address_space(1))) const void g_void;
typedef __attribute__((address_space(3))) void l_void;

__device__ __forceinline__ unsigned short f2bf(float x) {
    union { __hip_bfloat16 h; unsigned short u; } cv;
    cv.h = __float2bfloat16(x);   // RNE
    return cv.u;
}

// barrier WITHOUT vmcnt drain (keeps async global_load_lds in flight)
#define BAR() asm volatile("s_waitcnt lgkmcnt(0)\n\ts_barrier" ::: "memory")
#define WAIT_VM8() asm volatile("s_waitcnt vmcnt(8)" ::: "memory")

// ---------------- pre-pass: fp32 -> bf16 conversions ----------------
__global__ void cvt_q_kernel(const float* __restrict__ in, unsigned short* __restrict__ q) {
    const size_t i = (size_t)blockIdx.x * blockDim.x + threadIdx.x;   // one float4 per thread
    const float4 v = ((const float4*)in)[i];
    u16x4 o = { f2bf(v.x), f2bf(v.y), f2bf(v.z), f2bf(v.w) };
    ((u16x4*)q)[i] = o;
}

// W fp32 [p][m][c] -> wb bf16 [p][m][c] and wt bf16 [p][c][m] (32x32 LDS tile transpose)
__global__ void cvt_w_kernel(const float* __restrict__ w,
                             unsigned short* __restrict__ wb,
                             unsigned short* __restrict__ wt) {
    __shared__ float t[32][33];
    const int bid = blockIdx.x;
    const int p  = bid >> 11;              // 2048 tiles per p (64 m-tiles * 32 c-tiles)
    const int m0 = ((bid >> 5) & 63) << 5;
    const int c0 = (bid & 31) << 5;
    const int tx = threadIdx.x & 7;        // c quad
    const int ty = threadIdx.x >> 3;       // m row 0..31
    const float4 v = *(const float4*)(w + ((size_t)p*M_SZ + m0 + ty)*C_SZ + c0 + tx*4);
    u16x4 o = { f2bf(v.x), f2bf(v.y), f2bf(v.z), f2bf(v.w) };
    *(u16x4*)(wb + ((size_t)p*M_SZ + m0 + ty)*C_SZ + c0 + tx*4) = o;
    t[ty][tx*4+0] = v.x; t[ty][tx*4+1] = v.y; t[ty][tx*4+2] = v.z; t[ty][tx*4+3] = v.w;
    __syncthreads();
    float4 u2;
    u2.x = t[tx*4+0][ty]; u2.y = t[tx*4+1][ty]; u2.z = t[tx*4+2][ty]; u2.w = t[tx*4+3][ty];
    u16x4 o2 = { f2bf(u2.x), f2bf(u2.y), f2bf(u2.z), f2bf(u2.w) };
    *(u16x4*)(wt + ((size_t)p*C_SZ + c0 + ty)*M_SZ + m0 + tx*4) = o2;
}

// ---------------- main fused kernel ----------------
// 512 threads (8 waves), BR=64 rows of one p, MT=32 m-tiles, NT=64.
// GEMM1 waves = (rh row-half 32) x (kq K-quarter 256): Q in regs (2rf x 8kc), each
//   Ws B-frag feeds 2 MFMAs. 4-way K partials exchanged via Sred; wave (rh,kq)
//   finalizes frag fid=rh*4+kq: sum, exp, Ps write, per-lane denom accumulation.
// GEMM2 waves = (rh row-half) x (cq c-quarter 256): A from Ps, B from WsT (direct),
//   each B-frag feeds 2 MFMAs. acc[2][16] facc.
// Async staging: global_load_lds 16B, counted vmcnt(8), raw s_barrier (no vm drain).
// Ws read only by GEMM1, WsT only by GEMM2 -> phase-disjoint, no double buffer.
constexpr int NTHREADS = 512;
constexpr int BR = 64;
constexpr int MT = 32;
constexpr int NT = M_SZ / MT;            // 64

constexpr int WS_OFF   = 0;              // Ws  [32 m][128 chunk16B] (XOR-swz chunks): 65536 B
constexpr int WST_OFF  = 65536;          // WsT [1024 c][32 m] bf16 (pitch 64B): 65536 B
constexpr int SRED_OFF = 131072;         // Sred[8 fid][3 slot][16][18] f32: 27648 B
constexpr int PS_OFF   = 158720;         // Ps  [64 b][32 m] bf16 (pitch 64B): 4096 B
constexpr int DEN_OFF  = 162816;         // DEN [8 fid][16] f32: 512 B
constexpr int LDS_BYTES = 163328;        // <= 163840

__device__ __forceinline__ void stage_ws(const unsigned short* wsrcTile, char* ldsWs, int tid) {
    #pragma unroll
    for (int k = 0; k < 8; ++k) {
        const int o = k*8192 + tid*16;
        const int m = o >> 11;                 // row 0..31
        const int s = (o & 2047) >> 4;         // 16B chunk 0..127
        const unsigned short* src = wsrcTile + (size_t)m*C_SZ + ((s ^ (m & 7)) << 3);
        char* dst = ldsWs + k*8192 + ((tid >> 6) << 10);   // wave-uniform base; HW adds lane*16
        __builtin_amdgcn_global_load_lds((g_void*)src, (l_void*)dst, 16, 0, 0);
    }
}

__device__ __forceinline__ void stage_wst(const unsigned short* wtsrcTile, char* ldsWsT, int tid) {
    #pragma unroll
    for (int k = 0; k < 8; ++k) {
        const int o = k*8192 + tid*16;
        const int c  = o >> 6;                 // 0..1023
        const int mh = (o & 63) >> 4;          // 8-elem m chunk 0..3
        const unsigned short* src = wtsrcTile + (size_t)c*M_SZ + mh*8;
        char* dst = ldsWsT + k*8192 + ((tid >> 6) << 10);
        __builtin_amdgcn_global_load_lds((g_void*)src, (l_void*)dst, 16, 0, 0);
    }
}

__global__ __launch_bounds__(NTHREADS, 2)
void emu_main(const unsigned short* __restrict__ qB,
              const unsigned short* __restrict__ wB,
              const unsigned short* __restrict__ wtB,
              float* __restrict__ out)
{
    extern __shared__ char lds[];
    const int tid  = threadIdx.x;
    const int lane = tid & 63;
    const int wid  = tid >> 6;
    const int rh   = wid >> 2;     // row-half (32 rows)
    const int kq   = wid & 3;      // GEMM1 K-quarter / GEMM2 c-quarter
    const int g    = lane >> 4;    // k-group
    const int l15  = lane & 15;

    const int p    = blockIdx.x & 7;          // p pinned per XCD
    const int row0 = (blockIdx.x >> 3) * BR;

    const unsigned short* wbp = wB  + (size_t)p * M_SZ * C_SZ;
    const unsigned short* wtp = wtB + (size_t)p * C_SZ * M_SZ;

    // ---- preload Q fragments: rows (rh*2+rf)*16 + l15, K-quarter kq ----
    bfrag qreg[2][8];
    #pragma unroll
    for (int rf = 0; rf < 2; ++rf) {
        const int qrow = row0 + (rh*2 + rf)*16 + l15;
        const unsigned short* qp = qB + (size_t)qrow*C_SZ + kq*256 + g*8;
        #pragma unroll
        for (int kc = 0; kc < 8; ++kc)
            qreg[rf][kc] = *(const bfrag*)(qp + kc*32);
    }

    facc acc[2][16];
    #pragma unroll
    for (int i = 0; i < 2; ++i)
        #pragma unroll
        for (int j = 0; j < 16; ++j) acc[i][j] = facc{0.f,0.f,0.f,0.f};
    float dsum[4] = {0.f, 0.f, 0.f, 0.f};

    const int fid    = rh*4 + kq;            // frag this wave finalizes
    const int rf_own = rh*2 + (kq >> 1);
    const int mf_own = kq & 1;

    // prologue: stage tile 0
    stage_ws (wbp, lds + WS_OFF,  tid);
    stage_wst(wtp, lds + WST_OFF, tid);

    for (int mt = 0; mt < NT; ++mt) {
        const int mtn = (mt + 1 < NT) ? (mt + 1) : (NT - 1);

        WAIT_VM8();          // Ws(mt) landed (WsT(mt) still in flight)
        BAR();               // B1

        // ---------- GEMM1: partial S over K-quarter kq ----------
        facc sacc[2][2];
        #pragma unroll
        for (int i = 0; i < 2; ++i) { sacc[i][0] = facc{0,0,0,0}; sacc[i][1] = facc{0,0,0,0}; }
        {
            const char* wsr0 = lds + WS_OFF + l15*2048;          // m = l15
            const char* wsr1 = wsr0 + 32768;                     // m = 16+l15
            const int xr = l15 & 7;
            #pragma unroll
            for (int kc = 0; kc < 8; ++kc) {
                const int slog = kq*32 + kc*4 + g;
                const int off  = (slog ^ xr) << 4;
                bfrag b0 = *(const bfrag*)(wsr0 + off);
                bfrag b1 = *(const bfrag*)(wsr1 + off);
                #pragma unroll
                for (int rf = 0; rf < 2; ++rf) {
                    sacc[rf][0] = __builtin_amdgcn_mfma_f32_16x16x32_bf16(qreg[rf][kc], b0, sacc[rf][0], 0, 0, 0);
                    sacc[rf][1] = __builtin_amdgcn_mfma_f32_16x16x32_bf16(qreg[rf][kc], b1, sacc[rf][1], 0, 0, 0);
                }
            }
        }

        // ---------- write 3 partials to Sred (skip own) ----------
        #pragma unroll
        for (int j2 = 0; j2 < 4; ++j2) {
            if (j2 != kq) {
                const int s = kq - (kq > j2 ? 1 : 0);
                float* dstp = (float*)(lds + SRED_OFF) + ((rh*4 + j2)*3 + s)*288;
                #pragma unroll
                for (int j = 0; j < 4; ++j)
                    dstp[(g*4 + j)*18 + l15] = sacc[j2 >> 1][j2 & 1][j];
            }
        }
        BAR();               // B2 (Sred visible; Ws(mt) free)

        stage_ws(wbp + (size_t)mtn*MT*C_SZ, lds + WS_OFF, tid);   // prefetch Ws(mt+1)

        // ---------- finalize own frag: sum partials, exp, Ps, denom ----------
        {
            facc own = (kq == 0) ? sacc[0][0] : (kq == 1) ? sacc[0][1]
                     : (kq == 2) ? sacc[1][0] : sacc[1][1];
            const float* srcp = (const float*)(lds + SRED_OFF) + fid*3*288;
            float ps[4];
            #pragma unroll
            for (int j = 0; j < 4; ++j) {
                const int e = (g*4 + j)*18 + l15;
                float v = own[j] + srcp[e] + srcp[288 + e] + srcp[576 + e];
                ps[j] = __expf(v);
                dsum[j] += ps[j];
            }
            #pragma unroll
            for (int j = 0; j < 4; ++j)
                *(unsigned short*)(lds + PS_OFF + ((rf_own*16 + g*4 + j)*32 + mf_own*16 + l15)*2)
                    = f2bf(ps[j]);
        }

        WAIT_VM8();          // WsT(mt) landed (Ws(mt+1) still in flight)
        BAR();               // B3 (Ps visible; WsT ready)

        // ---------- GEMM2: O[rh 32 rows][cq 256 c] += P * W ----------
        {
            bfrag pa0 = *(const bfrag*)(lds + PS_OFF + ((rh*2 + 0)*16 + l15)*64 + g*16);
            bfrag pa1 = *(const bfrag*)(lds + PS_OFF + ((rh*2 + 1)*16 + l15)*64 + g*16);
            const char* wtb = lds + WST_OFF + (kq*256 + l15)*64 + g*16;
            #pragma unroll
            for (int cf = 0; cf < 16; ++cf) {
                bfrag bw = *(const bfrag*)(wtb + cf*1024);    // c += 16 -> 16*64B
                acc[0][cf] = __builtin_amdgcn_mfma_f32_16x16x32_bf16(pa0, bw, acc[0][cf], 0, 0, 0);
                acc[1][cf] = __builtin_amdgcn_mfma_f32_16x16x32_bf16(pa1, bw, acc[1][cf], 0, 0, 0);
            }
        }
        BAR();               // B4 (WsT free, Ps free)

        stage_wst(wtp + (size_t)mtn*MT, lds + WST_OFF, tid);      // prefetch WsT(mt+1)
    }

    // ---------- denom exchange ----------
    #pragma unroll
    for (int j = 0; j < 4; ++j) {
        float v = dsum[j];
        v += __shfl_xor(v, 1); v += __shfl_xor(v, 2);
        v += __shfl_xor(v, 4); v += __shfl_xor(v, 8);
        if (l15 == 0) ((float*)(lds + DEN_OFF))[fid*16 + g*4 + j] = v;
    }
    BAR();

    // ---------- epilogue: divide by denom, store ----------
    const float* denp = (const float*)(lds + DEN_OFF);
    #pragma unroll
    for (int rf = 0; rf < 2; ++rf) {
        const int rfg = rh*2 + rf;
        #pragma unroll
        for (int j = 0; j < 4; ++j) {
            const int rr = g*4 + j;
            const float inv = 1.0f / (denp[(rfg*2 + 0)*16 + rr] + denp[(rfg*2 + 1)*16 + rr]);
            const size_t b = (size_t)row0 + rfg*16 + rr;
            float* op = out + (b*P_SZ + p)*C_SZ + kq*256 + l15;
            #pragma unroll
            for (int cf = 0; cf < 16; ++cf)
                op[cf*16] = acc[rf][cf][j] * inv;
        }
    }
}

// ---------------- emergency fallback (no workspace): fp32, slow but correct ----------------
__global__ void emu_fallback(const float* __restrict__ inF, const float* __restrict__ wF,
                             float* __restrict__ out)
{
    __shared__ float sc[M_SZ];
    __shared__ float qs[C_SZ];
    __shared__ float wsum[4];
    const int b = blockIdx.x;
    const int tid = threadIdx.x;           // 256
    for (int c = tid; c < C_SZ; c += 256) qs[c] = inF[(size_t)b*C_SZ + c];
    __syncthreads();
    for (int p = 0; p < P_SZ; ++p) {
        const float* wp = wF + (size_t)p*M_SZ*C_SZ;
        for (int m = tid; m < M_SZ; m += 256) {
            float d = 0.f;
            const float* wr = wp + (size_t)m*C_SZ;
            for (int c = 0; c < C_SZ; ++c) d += qs[c]*wr[c];
            sc[m] = __expf(d);
        }
        __syncthreads();
        float part = 0.f;
        for (int m = tid; m < M_SZ; m += 256) part += sc[m];
        #pragma unroll
        for (int sft = 1; sft < 64; sft <<= 1) part += __shfl_xor(part, sft);
        if ((tid & 63) == 0) wsum[tid >> 6] = part;
        __syncthreads();
        const float rin = 1.0f / (wsum[0] + wsum[1] + wsum[2] + wsum[3]);
        float o0=0,o1=0,o2=0,o3=0;
        for (int m = 0; m < M_SZ; ++m) {
            const float pm = sc[m];
            const float4 w4 = *(const float4*)(wp + (size_t)m*C_SZ + tid*4);
            o0 += pm*w4.x; o1 += pm*w4.y; o2 += pm*w4.z; o3 += pm*w4.w;
        }
        float* op = out + ((size_t)b*P_SZ + p)*C_SZ + tid*4;
        op[0]=o0*rin; op[1]=o1*rin; op[2]=o2*rin; op[3]=o3*rin;
        __syncthreads();
    }
}

// ---------------- launcher ----------------
extern "C" void kernel_launch(void* const* d_in, const int* in_sizes, int n_in,
                              void* d_out, int out_size, void* d_ws, size_t ws_size,
                              hipStream_t stream)
{
    (void)in_sizes; (void)n_in; (void)out_size;
    const float* inF = (const float*)d_in[0];
    const float* wF  = (const float*)d_in[1];
    float* out = (float*)d_out;

    const size_t wbElems = (size_t)P_SZ * M_SZ * C_SZ;   // 16M
    const size_t qElems  = (size_t)B_SZ * C_SZ;          // 8M
    const size_t need = (wbElems*2 + qElems) * sizeof(unsigned short);  // ~84 MB

    if (ws_size >= need) {
        unsigned short* wb = (unsigned short*)d_ws;
        unsigned short* wt = wb + wbElems;
        unsigned short* qb = wt + wbElems;
        cvt_q_kernel<<<(unsigned)(qElems/4/256), 256, 0, stream>>>(inF, qb);
        cvt_w_kernel<<<P_SZ*64*32, 256, 0, stream>>>(wF, wb, wt);
        hipFuncSetAttribute(reinterpret_cast<const void*>(&emu_main),
                            hipFuncAttributeMaxDynamicSharedMemorySize, LDS_BYTES);
        const dim3 grid((B_SZ / BR) * P_SZ);   // 1024 blocks: p = bid&7
        emu_main<<<grid, dim3(NTHREADS), LDS_BYTES, stream>>>(qb, wb, wt, out);
    } else {
        emu_fallback<<<B_SZ, 256, 0, stream>>>(inF, wF, out);
    }
}

// Round 3
// 760.346 us; speedup vs baseline: 2.3472x; 1.7010x over previous
//
#include <hip/hip_runtime.h>
#include <hip/hip_bf16.h>
#include <cstdint>
#include <cstddef>

// Problem sizes (fixed)
#define B_SZ 8192
#define P_SZ 8
#define M_SZ 2048
#define C_SZ 1024

using bfrag = __attribute__((ext_vector_type(8))) short;          // 8 bf16 = 4 VGPR (MFMA A/B)
using facc  = __attribute__((ext_vector_type(4))) float;          // MFMA C/D frag
using u16x4 = __attribute__((ext_vector_type(4))) unsigned short;

typedef __attribute__((address_space(1))) const void g_void;
typedef __attribute__((address_space(3))) void l_void;

__device__ __forceinline__ unsigned short f2bf(float x) {
    union { __hip_bfloat16 h; unsigned short u; } cv;
    cv.h = __float2bfloat16(x);   // RNE
    return cv.u;
}
__device__ __forceinline__ float bf2f(unsigned short u) {
    union { unsigned int i; float f; } cv;
    cv.i = ((unsigned int)u) << 16;
    return cv.f;
}

// raw barriers that do NOT drain vmcnt (keep async global_load_lds in flight)
#define S_BARRIER()     asm volatile("s_barrier" ::: "memory")
#define LGKM0_BARRIER() asm volatile("s_waitcnt lgkmcnt(0)\n\ts_barrier" ::: "memory")
#define WAIT_VM(n)      asm volatile("s_waitcnt vmcnt(" #n ")" ::: "memory")
// round-2 fused-kernel macros
#define BAR() asm volatile("s_waitcnt lgkmcnt(0)\n\ts_barrier" ::: "memory")
#define WAIT_VM8() asm volatile("s_waitcnt vmcnt(8)" ::: "memory")

// ---------------- pre-pass: fp32 -> bf16 conversions ----------------
__global__ void cvt_q_kernel(const float* __restrict__ in, unsigned short* __restrict__ q) {
    const size_t i = (size_t)blockIdx.x * blockDim.x + threadIdx.x;   // one float4 per thread
    const float4 v = ((const float4*)in)[i];
    u16x4 o = { f2bf(v.x), f2bf(v.y), f2bf(v.z), f2bf(v.w) };
    ((u16x4*)q)[i] = o;
}

// W fp32 [p][m][c] -> wb bf16 [p][m][c] and wt bf16 [p][c][m] (32x32 LDS tile transpose)
__global__ void cvt_w_kernel(const float* __restrict__ w,
                             unsigned short* __restrict__ wb,
                             unsigned short* __restrict__ wt) {
    __shared__ float t[32][33];
    const int bid = blockIdx.x;
    const int p  = bid >> 11;              // 2048 tiles per p (64 m-tiles * 32 c-tiles)
    const int m0 = ((bid >> 5) & 63) << 5;
    const int c0 = (bid & 31) << 5;
    const int tx = threadIdx.x & 7;        // c quad
    const int ty = threadIdx.x >> 3;       // m row 0..31
    const float4 v = *(const float4*)(w + ((size_t)p*M_SZ + m0 + ty)*C_SZ + c0 + tx*4);
    u16x4 o = { f2bf(v.x), f2bf(v.y), f2bf(v.z), f2bf(v.w) };
    *(u16x4*)(wb + ((size_t)p*M_SZ + m0 + ty)*C_SZ + c0 + tx*4) = o;
    t[ty][tx*4+0] = v.x; t[ty][tx*4+1] = v.y; t[ty][tx*4+2] = v.z; t[ty][tx*4+3] = v.w;
    __syncthreads();
    float4 u2;
    u2.x = t[tx*4+0][ty]; u2.y = t[tx*4+1][ty]; u2.z = t[tx*4+2][ty]; u2.w = t[tx*4+3][ty];
    u16x4 o2 = { f2bf(u2.x), f2bf(u2.y), f2bf(u2.z), f2bf(u2.w) };
    *(u16x4*)(wt + ((size_t)p*C_SZ + c0 + ty)*M_SZ + m0 + tx*4) = o2;
}

// ================= decoupled GEMM core (m97-class, 128x128 tile, BK=32) =================
// 256 threads = 4 waves in 2x2 grid; per-wave C = 64x64 = acc[4][4] facc.
// LDS: 2 buffers x (A 8KB + B 8KB) = 32KB -> 3-4 blocks/CU.
// A: [AM][KLEN] bf16 row-major; Bm: [BN][KLEN] bf16 row-major (B^T layout).
// Staging: global_load_lds 16B, linear LDS dest, inverse-XOR-swizzled global source:
//   row r (64B in LDS), chunk slot s holds global chunk cs = s ^ ((r>>1)&3)
//   -> ds_read_b128 of a 16-lane column-slice hits each bank exactly 2x (free).
// Pipeline: depth-2 counted vmcnt(4); raw s_barrier (loads stay in flight).
// MODE 0 (scores): epilogue exp -> P bf16 [row][M_SZ].
// MODE 1 (combine): in-loop row-sum of A-frags = softmax denominator (K covers all m);
//                   epilogue divides and writes out[b][p][c] f32.
template<int KLEN, int NTN, int CPX, int MODE>
__global__ __launch_bounds__(256, 2)
void gemm_tile(const unsigned short* __restrict__ A,
               const unsigned short* __restrict__ Bm,
               unsigned short* __restrict__ Pout,
               float* __restrict__ Oout,
               int p)
{
    __shared__ alignas(16) char lds[32768];
    const int tid  = threadIdx.x;
    const int lane = tid & 63;
    const int wid  = tid >> 6;
    const int wr   = wid >> 1;    // wave row (64 rows)
    const int wc   = wid & 1;     // wave col (64 cols)
    const int g    = lane >> 4;   // k-chunk group
    const int l15  = lane & 15;

    // bijective XCD chunking: each XCD gets CPX consecutive logical tiles
    const int logical = (blockIdx.x & 7) * CPX + (blockIdx.x >> 3);
    const int mt = logical / NTN;
    const int nt = logical % NTN;

    const unsigned short* Abase = A  + (size_t)mt * 128 * KLEN;
    const unsigned short* Bbase = Bm + (size_t)nt * 128 * KLEN;

    facc acc[4][4];
    #pragma unroll
    for (int i = 0; i < 4; ++i)
        #pragma unroll
        for (int j = 0; j < 4; ++j) acc[i][j] = facc{0.f, 0.f, 0.f, 0.f};
    float rs[4] = {0.f, 0.f, 0.f, 0.f};   // MODE1: per-lane partial row sums

    constexpr int NKT = KLEN / 32;

    auto stage = [&](int kt) {
        char* buf = lds + (kt & 1) * 16384;
        const unsigned short* As = Abase + kt * 32;
        const unsigned short* Bs = Bbase + kt * 32;
        #pragma unroll
        for (int i = 0; i < 2; ++i) {
            const int o  = i * 4096 + tid * 16;
            const int r  = o >> 6;               // LDS row (64B)
            const int s  = (o >> 4) & 3;         // chunk slot in row
            const int cs = s ^ ((r >> 1) & 3);   // inverse swizzle on global source
            __builtin_amdgcn_global_load_lds((g_void*)(As + (size_t)r * KLEN + cs * 8),
                                             (l_void*)(buf + i * 4096 + ((tid >> 6) << 10)),
                                             16, 0, 0);
        }
        #pragma unroll
        for (int i = 0; i < 2; ++i) {
            const int o  = i * 4096 + tid * 16;
            const int r  = o >> 6;
            const int s  = (o >> 4) & 3;
            const int cs = s ^ ((r >> 1) & 3);
            __builtin_amdgcn_global_load_lds((g_void*)(Bs + (size_t)r * KLEN + cs * 8),
                                             (l_void*)(buf + 8192 + i * 4096 + ((tid >> 6) << 10)),
                                             16, 0, 0);
        }
    };

    stage(0);
    stage(1);

    const int cb = ((((l15 >> 1) & 3) ^ g) << 4);   // swizzled chunk byte offset for reads

    for (int kt = 0; kt < NKT; ++kt) {
        if (kt + 1 < NKT) { WAIT_VM(4); } else { WAIT_VM(0); }
        S_BARRIER();                                  // tile kt fully landed (all waves)
        const char* Ab = lds + (kt & 1) * 16384;
        const char* Bb = Ab + 8192;
        bfrag af[4], bb[4];
        #pragma unroll
        for (int mf = 0; mf < 4; ++mf)
            af[mf] = *(const bfrag*)(Ab + (wr * 64 + mf * 16 + l15) * 64 + cb);
        #pragma unroll
        for (int nf = 0; nf < 4; ++nf)
            bb[nf] = *(const bfrag*)(Bb + (wc * 64 + nf * 16 + l15) * 64 + cb);
        LGKM0_BARRIER();                              // all reads done -> safe to overwrite
        if (kt + 2 < NKT) stage(kt + 2);              // overlaps with MFMA below
        if (MODE == 1) {
            #pragma unroll
            for (int mf = 0; mf < 4; ++mf)
                #pragma unroll
                for (int e = 0; e < 8; ++e)
                    rs[mf] += bf2f((unsigned short)af[mf][e]);
        }
        #pragma unroll
        for (int mf = 0; mf < 4; ++mf)
            #pragma unroll
            for (int nf = 0; nf < 4; ++nf)
                acc[mf][nf] = __builtin_amdgcn_mfma_f32_16x16x32_bf16(af[mf], bb[nf], acc[mf][nf], 0, 0, 0);
    }

    if (MODE == 0) {
        // scores -> exp -> P bf16 [8192][2048]
        const int prow0 = mt * 128 + wr * 64;
        const int pcol0 = nt * 128 + wc * 64;
        #pragma unroll
        for (int mf = 0; mf < 4; ++mf)
            #pragma unroll
            for (int j = 0; j < 4; ++j) {
                const size_t rbase = (size_t)(prow0 + mf * 16 + g * 4 + j) * M_SZ + pcol0 + l15;
                #pragma unroll
                for (int nf = 0; nf < 4; ++nf)
                    Pout[rbase + nf * 16] = f2bf(__expf(acc[mf][nf][j]));
            }
    } else {
        // combine: divide by denominator, write out[b][p][c] f32
        const int orow0 = mt * 128 + wr * 64;
        const int ocol0 = nt * 128 + wc * 64;
        #pragma unroll
        for (int mf = 0; mf < 4; ++mf) {
            float d = rs[mf];
            d += __shfl_xor(d, 16);
            d += __shfl_xor(d, 32);    // full row sum for row (mf*16 + l15)
            #pragma unroll
            for (int j = 0; j < 4; ++j) {
                const float inv = 1.0f / __shfl(d, g * 4 + j);   // denom of C-row g*4+j
                const size_t rbase = ((size_t)(orow0 + mf * 16 + g * 4 + j) * P_SZ + p) * C_SZ
                                   + ocol0 + l15;
                #pragma unroll
                for (int nf = 0; nf < 4; ++nf)
                    Oout[rbase + nf * 16] = acc[mf][nf][j] * inv;
            }
        }
    }
}

// ================= round-2 fused kernel (middle-tier fallback, proven) =================
constexpr int NTHREADS = 512;
constexpr int BR = 64;
constexpr int MT = 32;
constexpr int NT = M_SZ / MT;            // 64

constexpr int WS_OFF   = 0;              // Ws  [32 m][128 chunk16B] (XOR-swz chunks): 65536 B
constexpr int WST_OFF  = 65536;          // WsT [1024 c][32 m] bf16 (pitch 64B): 65536 B
constexpr int SRED_OFF = 131072;         // Sred[8 fid][3 slot][16][18] f32: 27648 B
constexpr int PS_OFF   = 158720;         // Ps  [64 b][32 m] bf16 (pitch 64B): 4096 B
constexpr int DEN_OFF  = 162816;         // DEN [8 fid][16] f32: 512 B
constexpr int LDS_BYTES = 163328;        // <= 163840

__device__ __forceinline__ void stage_ws(const unsigned short* wsrcTile, char* ldsWs, int tid) {
    #pragma unroll
    for (int k = 0; k < 8; ++k) {
        const int o = k*8192 + tid*16;
        const int m = o >> 11;
        const int s = (o & 2047) >> 4;
        const unsigned short* src = wsrcTile + (size_t)m*C_SZ + ((s ^ (m & 7)) << 3);
        char* dst = ldsWs + k*8192 + ((tid >> 6) << 10);
        __builtin_amdgcn_global_load_lds((g_void*)src, (l_void*)dst, 16, 0, 0);
    }
}

__device__ __forceinline__ void stage_wst(const unsigned short* wtsrcTile, char* ldsWsT, int tid) {
    #pragma unroll
    for (int k = 0; k < 8; ++k) {
        const int o = k*8192 + tid*16;
        const int c  = o >> 6;
        const int mh = (o & 63) >> 4;
        const unsigned short* src = wtsrcTile + (size_t)c*M_SZ + mh*8;
        char* dst = ldsWsT + k*8192 + ((tid >> 6) << 10);
        __builtin_amdgcn_global_load_lds((g_void*)src, (l_void*)dst, 16, 0, 0);
    }
}

__global__ __launch_bounds__(NTHREADS, 2)
void emu_main(const unsigned short* __restrict__ qB,
              const unsigned short* __restrict__ wB,
              const unsigned short* __restrict__ wtB,
              float* __restrict__ out)
{
    extern __shared__ char lds[];
    const int tid  = threadIdx.x;
    const int lane = tid & 63;
    const int wid  = tid >> 6;
    const int rh   = wid >> 2;
    const int kq   = wid & 3;
    const int g    = lane >> 4;
    const int l15  = lane & 15;

    const int p    = blockIdx.x & 7;
    const int row0 = (blockIdx.x >> 3) * BR;

    const unsigned short* wbp = wB  + (size_t)p * M_SZ * C_SZ;
    const unsigned short* wtp = wtB + (size_t)p * C_SZ * M_SZ;

    bfrag qreg[2][8];
    #pragma unroll
    for (int rf = 0; rf < 2; ++rf) {
        const int qrow = row0 + (rh*2 + rf)*16 + l15;
        const unsigned short* qp = qB + (size_t)qrow*C_SZ + kq*256 + g*8;
        #pragma unroll
        for (int kc = 0; kc < 8; ++kc)
            qreg[rf][kc] = *(const bfrag*)(qp + kc*32);
    }

    facc acc[2][16];
    #pragma unroll
    for (int i = 0; i < 2; ++i)
        #pragma unroll
        for (int j = 0; j < 16; ++j) acc[i][j] = facc{0.f,0.f,0.f,0.f};
    float dsum[4] = {0.f, 0.f, 0.f, 0.f};

    const int fid    = rh*4 + kq;
    const int rf_own = rh*2 + (kq >> 1);
    const int mf_own = kq & 1;

    stage_ws (wbp, lds + WS_OFF,  tid);
    stage_wst(wtp, lds + WST_OFF, tid);

    for (int mt = 0; mt < NT; ++mt) {
        const int mtn = (mt + 1 < NT) ? (mt + 1) : (NT - 1);

        WAIT_VM8();
        BAR();

        facc sacc[2][2];
        #pragma unroll
        for (int i = 0; i < 2; ++i) { sacc[i][0] = facc{0,0,0,0}; sacc[i][1] = facc{0,0,0,0}; }
        {
            const char* wsr0 = lds + WS_OFF + l15*2048;
            const char* wsr1 = wsr0 + 32768;
            const int xr = l15 & 7;
            #pragma unroll
            for (int kc = 0; kc < 8; ++kc) {
                const int slog = kq*32 + kc*4 + g;
                const int off  = (slog ^ xr) << 4;
                bfrag b0 = *(const bfrag*)(wsr0 + off);
                bfrag b1 = *(const bfrag*)(wsr1 + off);
                #pragma unroll
                for (int rf = 0; rf < 2; ++rf) {
                    sacc[rf][0] = __builtin_amdgcn_mfma_f32_16x16x32_bf16(qreg[rf][kc], b0, sacc[rf][0], 0, 0, 0);
                    sacc[rf][1] = __builtin_amdgcn_mfma_f32_16x16x32_bf16(qreg[rf][kc], b1, sacc[rf][1], 0, 0, 0);
                }
            }
        }

        #pragma unroll
        for (int j2 = 0; j2 < 4; ++j2) {
            if (j2 != kq) {
                const int s = kq - (kq > j2 ? 1 : 0);
                float* dstp = (float*)(lds + SRED_OFF) + ((rh*4 + j2)*3 + s)*288;
                #pragma unroll
                for (int j = 0; j < 4; ++j)
                    dstp[(g*4 + j)*18 + l15] = sacc[j2 >> 1][j2 & 1][j];
            }
        }
        BAR();

        stage_ws(wbp + (size_t)mtn*MT*C_SZ, lds + WS_OFF, tid);

        {
            facc own = (kq == 0) ? sacc[0][0] : (kq == 1) ? sacc[0][1]
                     : (kq == 2) ? sacc[1][0] : sacc[1][1];
            const float* srcp = (const float*)(lds + SRED_OFF) + fid*3*288;
            float ps[4];
            #pragma unroll
            for (int j = 0; j < 4; ++j) {
                const int e = (g*4 + j)*18 + l15;
                float v = own[j] + srcp[e] + srcp[288 + e] + srcp[576 + e];
                ps[j] = __expf(v);
                dsum[j] += ps[j];
            }
            #pragma unroll
            for (int j = 0; j < 4; ++j)
                *(unsigned short*)(lds + PS_OFF + ((rf_own*16 + g*4 + j)*32 + mf_own*16 + l15)*2)
                    = f2bf(ps[j]);
        }

        WAIT_VM8();
        BAR();

        {
            bfrag pa0 = *(const bfrag*)(lds + PS_OFF + ((rh*2 + 0)*16 + l15)*64 + g*16);
            bfrag pa1 = *(const bfrag*)(lds + PS_OFF + ((rh*2 + 1)*16 + l15)*64 + g*16);
            const char* wtb = lds + WST_OFF + (kq*256 + l15)*64 + g*16;
            #pragma unroll
            for (int cf = 0; cf < 16; ++cf) {
                bfrag bw = *(const bfrag*)(wtb + cf*1024);
                acc[0][cf] = __builtin_amdgcn_mfma_f32_16x16x32_bf16(pa0, bw, acc[0][cf], 0, 0, 0);
                acc[1][cf] = __builtin_amdgcn_mfma_f32_16x16x32_bf16(pa1, bw, acc[1][cf], 0, 0, 0);
            }
        }
        BAR();

        stage_wst(wtp + (size_t)mtn*MT, lds + WST_OFF, tid);
    }

    #pragma unroll
    for (int j = 0; j < 4; ++j) {
        float v = dsum[j];
        v += __shfl_xor(v, 1); v += __shfl_xor(v, 2);
        v += __shfl_xor(v, 4); v += __shfl_xor(v, 8);
        if (l15 == 0) ((float*)(lds + DEN_OFF))[fid*16 + g*4 + j] = v;
    }
    BAR();

    const float* denp = (const float*)(lds + DEN_OFF);
    #pragma unroll
    for (int rf = 0; rf < 2; ++rf) {
        const int rfg = rh*2 + rf;
        #pragma unroll
        for (int j = 0; j < 4; ++j) {
            const int rr = g*4 + j;
            const float inv = 1.0f / (denp[(rfg*2 + 0)*16 + rr] + denp[(rfg*2 + 1)*16 + rr]);
            const size_t b = (size_t)row0 + rfg*16 + rr;
            float* op = out + (b*P_SZ + p)*C_SZ + kq*256 + l15;
            #pragma unroll
            for (int cf = 0; cf < 16; ++cf)
                op[cf*16] = acc[rf][cf][j] * inv;
        }
    }
}

// ---------------- emergency fallback (no workspace): fp32, slow but correct ----------------
__global__ void emu_fallback(const float* __restrict__ inF, const float* __restrict__ wF,
                             float* __restrict__ out)
{
    __shared__ float sc[M_SZ];
    __shared__ float qs[C_SZ];
    __shared__ float wsum[4];
    const int b = blockIdx.x;
    const int tid = threadIdx.x;           // 256
    for (int c = tid; c < C_SZ; c += 256) qs[c] = inF[(size_t)b*C_SZ + c];
    __syncthreads();
    for (int p = 0; p < P_SZ; ++p) {
        const float* wp = wF + (size_t)p*M_SZ*C_SZ;
        for (int m = tid; m < M_SZ; m += 256) {
            float d = 0.f;
            const float* wr = wp + (size_t)m*C_SZ;
            for (int c = 0; c < C_SZ; ++c) d += qs[c]*wr[c];
            sc[m] = __expf(d);
        }
        __syncthreads();
        float part = 0.f;
        for (int m = tid; m < M_SZ; m += 256) part += sc[m];
        #pragma unroll
        for (int sft = 1; sft < 64; sft <<= 1) part += __shfl_xor(part, sft);
        if ((tid & 63) == 0) wsum[tid >> 6] = part;
        __syncthreads();
        const float rin = 1.0f / (wsum[0] + wsum[1] + wsum[2] + wsum[3]);
        float o0=0,o1=0,o2=0,o3=0;
        for (int m = 0; m < M_SZ; ++m) {
            const float pm = sc[m];
            const float4 w4 = *(const float4*)(wp + (size_t)m*C_SZ + tid*4);
            o0 += pm*w4.x; o1 += pm*w4.y; o2 += pm*w4.z; o3 += pm*w4.w;
        }
        float* op = out + ((size_t)b*P_SZ + p)*C_SZ + tid*4;
        op[0]=o0*rin; op[1]=o1*rin; op[2]=o2*rin; op[3]=o3*rin;
        __syncthreads();
    }
}

// ---------------- launcher ----------------
extern "C" void kernel_launch(void* const* d_in, const int* in_sizes, int n_in,
                              void* d_out, int out_size, void* d_ws, size_t ws_size,
                              hipStream_t stream)
{
    (void)in_sizes; (void)n_in; (void)out_size;
    const float* inF = (const float*)d_in[0];
    const float* wF  = (const float*)d_in[1];
    float* out = (float*)d_out;

    const size_t wbE = (size_t)P_SZ * M_SZ * C_SZ;   // 16M
    const size_t qE  = (size_t)B_SZ * C_SZ;          // 8M
    const size_t pME = (size_t)B_SZ * M_SZ;          // 16M (one p's P panel)
    const size_t needFull  = (wbE*2 + qE + pME) * sizeof(unsigned short);  // ~117 MB
    const size_t needFused = (wbE*2 + qE) * sizeof(unsigned short);        // ~84 MB

    if (ws_size >= needFull) {
        unsigned short* wb = (unsigned short*)d_ws;
        unsigned short* wt = wb + wbE;
        unsigned short* qb = wt + wbE;
        unsigned short* Pb = qb + qE;
        cvt_q_kernel<<<(unsigned)(qE/4/256), 256, 0, stream>>>(inF, qb);
        cvt_w_kernel<<<P_SZ*64*32, 256, 0, stream>>>(wF, wb, wt);
        for (int p = 0; p < P_SZ; ++p) {
            // GEMM1: S = Q * W_p^T -> exp -> P  (M=8192, N=2048, K=1024)
            gemm_tile<C_SZ, 16, 128, 0><<<1024, 256, 0, stream>>>(
                qb, wb + (size_t)p*M_SZ*C_SZ, Pb, nullptr, p);
            // GEMM2: O = P * W_p / denom      (M=8192, N=1024, K=2048)
            gemm_tile<M_SZ, 8, 64, 1><<<512, 256, 0, stream>>>(
                Pb, wt + (size_t)p*C_SZ*M_SZ, nullptr, out, p);
        }
    } else if (ws_size >= needFused) {
        unsigned short* wb = (unsigned short*)d_ws;
        unsigned short* wt = wb + wbE;
        unsigned short* qb = wt + wbE;
        cvt_q_kernel<<<(unsigned)(qE/4/256), 256, 0, stream>>>(inF, qb);
        cvt_w_kernel<<<P_SZ*64*32, 256, 0, stream>>>(wF, wb, wt);
        hipFuncSetAttribute(reinterpret_cast<const void*>(&emu_main),
                            hipFuncAttributeMaxDynamicSharedMemorySize, LDS_BYTES);
        const dim3 grid((B_SZ / BR) * P_SZ);
        emu_main<<<grid, dim3(NTHREADS), LDS_BYTES, stream>>>(qb, wb, wt, out);
    } else {
        emu_fallback<<<B_SZ, 256, 0, stream>>>(inF, wF, out);
    }
}